// Round 13
// baseline (1317.994 us; speedup 1.0000x reference)
//
#include <hip/hip_runtime.h>
#include <hip/hip_bf16.h>
#include <stdint.h>

typedef __bf16 bf16_t;
typedef __bf16 bf16x8 __attribute__((ext_vector_type(8)));
typedef float f32x4 __attribute__((ext_vector_type(4)));

#define B_ 2
#define S_ 4096
#define D_ 2048
#define H_ 16
#define HD_ 128
#define FF_ 8192
#define W_ 256
#define NB_ 16            // S_/W_
#define ROWS_ 8192        // B_*S_
#define QS_ 6144          // fused qkv row stride

#define BAR() asm volatile("s_barrier" ::: "memory")

// ------------------------------------------------- dtype-flex input helpers
__device__ __forceinline__ bool det_bf16(const uint32_t* det) {
  return (det[0] & 0xFFFFu) == 0x3F80u;
}
__device__ __forceinline__ float ldS(const void* p, size_t i, bool isbf) {
  return isbf ? (float)((const bf16_t*)p)[i] : ((const float*)p)[i];
}
__device__ __forceinline__ void ld8(const void* p, size_t i, bool isbf,
                                    float* f) {
  if (isbf) {
    bf16x8 v = *(const bf16x8*)((const bf16_t*)p + i);
#pragma unroll
    for (int j = 0; j < 8; ++j) f[j] = (float)v[j];
  } else {
    const float* s = (const float*)p + i;
    float4 a = *(const float4*)s;
    float4 b = *(const float4*)(s + 4);
    f[0] = a.x; f[1] = a.y; f[2] = a.z; f[3] = a.w;
    f[4] = b.x; f[5] = b.y; f[6] = b.z; f[7] = b.w;
  }
}

__device__ __forceinline__ void gld_lds16(const bf16_t* g, bf16_t* l) {
  __builtin_amdgcn_global_load_lds(
      (const __attribute__((address_space(1))) uint32_t*)g,
      (__attribute__((address_space(3))) uint32_t*)l, 16, 0, 0);
}

// ---------------------------------------------------------------- transpose
__global__ __launch_bounds__(256)
void transpose_k(const void* __restrict__ src, bf16_t* __restrict__ dst,
                 int R, int C, const uint32_t* __restrict__ det) {
  __shared__ __align__(16) bf16_t tile[64][72];
  const bool isbf = det_bf16(det);
  const int nbc = C >> 6;
  const int br = blockIdx.x / nbc, bc = blockIdx.x % nbc;
  const int t = threadIdx.x;
#pragma unroll
  for (int rnd = 0; rnd < 2; ++rnd) {
    int chunk = t + rnd * 256;
    int r = chunk >> 3;
    int c8 = (chunk & 7) << 3;
    float f[8];
    ld8(src, (size_t)(br * 64 + r) * C + bc * 64 + c8, isbf, f);
    union { bf16_t e[8]; int4 v; } u;
#pragma unroll
    for (int j = 0; j < 8; ++j) u.e[j] = (bf16_t)f[j];
    *(int4*)&tile[r][c8] = u.v;
  }
  __syncthreads();
#pragma unroll
  for (int rnd = 0; rnd < 2; ++rnd) {
    int chunk = t + rnd * 256;
    int cc = chunk >> 3;
    int r8 = (chunk & 7) << 3;
    union { bf16_t e[8]; int4 v; } u;
#pragma unroll
    for (int j = 0; j < 8; ++j) u.e[j] = tile[r8 + j][cc];
    *(int4*)&dst[(size_t)(bc * 64 + cc) * R + br * 64 + r8] = u.v;
  }
}

// ---------------------------------------------------------------- rmsnorm
__global__ __launch_bounds__(256)
void rmsnorm_in_k(const void* __restrict__ x, const void* __restrict__ w,
                  bf16_t* __restrict__ out, const uint32_t* __restrict__ det) {
  __shared__ float sm[4];
  const bool isbf = det_bf16(det);
  const size_t row = blockIdx.x;
  const int i0 = threadIdx.x << 3;
  float f[8], ss = 0.f;
  ld8(x, row * D_ + i0, isbf, f);
#pragma unroll
  for (int j = 0; j < 8; ++j) ss += f[j] * f[j];
#pragma unroll
  for (int off = 1; off < 64; off <<= 1) ss += __shfl_xor(ss, off, 64);
  if ((threadIdx.x & 63) == 0) sm[threadIdx.x >> 6] = ss;
  __syncthreads();
  float tot = sm[0] + sm[1] + sm[2] + sm[3];
  float rs = rsqrtf(tot * (1.0f / D_) + 1e-6f);
  float wf[8];
  ld8(w, i0, isbf, wf);
  bf16x8 res;
#pragma unroll
  for (int j = 0; j < 8; ++j) res[j] = (bf16_t)(f[j] * rs * wf[j]);
  *(bf16x8*)&out[row * D_ + i0] = res;
}

__global__ __launch_bounds__(256)
void rmsnorm_f32_k(const float* __restrict__ x, const void* __restrict__ w,
                   bf16_t* __restrict__ out, const uint32_t* __restrict__ det) {
  __shared__ float sm[4];
  const bool isbf = det_bf16(det);
  const size_t row = blockIdx.x;
  const int i0 = threadIdx.x << 3;
  float4 a = *(const float4*)&x[row * D_ + i0];
  float4 b = *(const float4*)&x[row * D_ + i0 + 4];
  float f[8] = {a.x, a.y, a.z, a.w, b.x, b.y, b.z, b.w};
  float ss = 0.f;
#pragma unroll
  for (int j = 0; j < 8; ++j) ss += f[j] * f[j];
#pragma unroll
  for (int off = 1; off < 64; off <<= 1) ss += __shfl_xor(ss, off, 64);
  if ((threadIdx.x & 63) == 0) sm[threadIdx.x >> 6] = ss;
  __syncthreads();
  float tot = sm[0] + sm[1] + sm[2] + sm[3];
  float rs = rsqrtf(tot * (1.0f / D_) + 1e-6f);
  float wf[8];
  ld8(w, i0, isbf, wf);
  bf16x8 res;
#pragma unroll
  for (int j = 0; j < 8; ++j) res[j] = (bf16_t)(f[j] * rs * wf[j]);
  *(bf16x8*)&out[row * D_ + i0] = res;
}

// ---------------------------------------------------------------- qk-norm + rope
__global__ __launch_bounds__(256)
void qknorm_rope_k(bf16_t* __restrict__ qkv, const void* __restrict__ qw,
                   const void* __restrict__ kw,
                   const uint32_t* __restrict__ det) {
  const bool isbf = det_bf16(det);
  const int wv = threadIdx.x >> 6;
  const int i = threadIdx.x & 63;
  const int idx = blockIdx.x * 4 + wv;   // (b*S + s)*H + h
  const int row = idx >> 4;              // b*S + s
  const int s = row & (S_ - 1);
  const int h = idx & 15;
  bf16_t* qp = qkv + (size_t)row * QS_ + h * HD_;
  bf16_t* kp = qp + 2048;

  float inv = exp2f((float)i * -0.20762050593046014f);  // 10000^(-i/64)
  float ang = (float)s * inv;
  float sn, cs;
  sincosf(ang, &sn, &cs);

#pragma unroll
  for (int t = 0; t < 2; ++t) {
    bf16_t* p = (t == 0) ? qp : kp;
    const void* w = (t == 0) ? qw : kw;
    float x1 = (float)p[i], x2 = (float)p[i + 64];
    float ss = x1 * x1 + x2 * x2;
#pragma unroll
    for (int off = 1; off < 64; off <<= 1) ss += __shfl_xor(ss, off, 64);
    float rs = rsqrtf(ss * (1.0f / HD_) + 1e-6f);
    float n1 = x1 * rs * ldS(w, i, isbf);
    float n2 = x2 * rs * ldS(w, i + 64, isbf);
    p[i] = (bf16_t)(n1 * cs - n2 * sn);
    p[i + 64] = (bf16_t)(n1 * sn + n2 * cs);
  }
}

// ---------------------------------------------------------------- GEMM 256x256
// 16-wave block (1024 thr), 4x4 wave grid, 64x64 per wave: acc = 64 regs,
// frags = 32, total ~120 <= 128 -> 4 waves/SIMD (vs 2 for the 8-wave/128x64
// shape whose 216-reg footprint capped occupancy). Doubles latency-hiding
// TLP; LDS frag traffic (128 KB/K-tile/CU = 512 cyc) stays under the MFMA
// floor (1242 cyc), so the structure remains MFMA-bound. Sync semantics
// identical to the validated dbuf: stage(t+1)->buf^1, vmcnt(0)+barrier per
// K-tile. Staging = 1 load/thread/operand. 2D-group mapping + XOR swizzle.
#define TQ 8192   // 256*32 elems per operand tile

template <int EPI>
__global__ __launch_bounds__(1024)
void gemm256_k(const bf16_t* __restrict__ A, const bf16_t* __restrict__ Bt,
               void* __restrict__ C, const void* __restrict__ aux,
               const uint32_t* __restrict__ det, int M, int N, int K) {
  extern __shared__ __align__(16) bf16_t lds[];
  bf16_t* Ab = lds;             // [2][256][32]
  bf16_t* Bb = lds + 2 * TQ;    // [2][256][32]

  bool isbf = false;
  if constexpr (EPI == 1 || EPI == 3) isbf = det_bf16(det);

  const int tid = threadIdx.x;
  const int lane = tid & 63, wid = tid >> 6;   // 16 waves
  const int l15 = lane & 15, l4 = lane >> 4;
  const int wr = wid >> 2, wc = wid & 3;       // 4x4 wave grid, 64x64 each

  // T1: bijective XCD swizzle (m204), then 2D group (GM=4)
  const int nwg = gridDim.x;
  const int nbn = N >> 8;
  const int orig = blockIdx.x;
  const int q8 = nwg >> 3, r8 = nwg & 7, xcd = orig & 7;
  const int swz = (xcd < r8 ? xcd * (q8 + 1) : r8 * (q8 + 1) + (xcd - r8) * q8)
                + (orig >> 3);
  const int grp = swz / (4 * nbn);
  const int rem = swz % (4 * nbn);
  const int bm = grp * 4 + (rem & 3);
  const int bn = rem >> 2;

  const bf16_t* Ag = A + (size_t)(bm * 256) * K;
  const bf16_t* Bg = Bt + (size_t)(bn * 256) * K;

  // staging: 1024 16B units per operand tile; exactly 1 per thread
  const int r0 = tid >> 2, u0 = tid & 3;
  const size_t goff = (size_t)r0 * K + ((u0 ^ ((r0 >> 1) & 3)) << 3);
  const int loff = tid * 8;

  auto stage = [&](int tt) {
    const size_t k0 = (size_t)tt << 5;
    gld_lds16(Ag + k0 + goff, Ab + (tt & 1) * TQ + loff);
    gld_lds16(Bg + k0 + goff, Bb + (tt & 1) * TQ + loff);
  };

  // read offsets (elems), thread-constant
  int aoff[4], boff[4];
#pragma unroll
  for (int m = 0; m < 4; ++m) {
    int R = wr * 64 + m * 16 + l15;
    aoff[m] = R * 32 + ((l4 ^ ((R >> 1) & 3)) << 3);
  }
#pragma unroll
  for (int n = 0; n < 4; ++n) {
    int R = wc * 64 + n * 16 + l15;
    boff[n] = R * 32 + ((l4 ^ ((R >> 1) & 3)) << 3);
  }

  f32x4 acc[4][4] = {};
  const int nt = K >> 5;

  // prologue: stage tile 0
  stage(0);
  asm volatile("s_waitcnt vmcnt(0)" ::: "memory");
  BAR();

  for (int t = 0; t < nt; ++t) {
    const bf16_t* a = Ab + (t & 1) * TQ;
    const bf16_t* b = Bb + (t & 1) * TQ;

    if (t + 1 < nt) stage(t + 1);   // into the other buffer

    bf16x8 af[4], bfr[4];
#pragma unroll
    for (int n = 0; n < 4; ++n) bfr[n] = *(const bf16x8*)&b[boff[n]];
#pragma unroll
    for (int m = 0; m < 4; ++m) af[m] = *(const bf16x8*)&a[aoff[m]];

#pragma unroll
    for (int m = 0; m < 4; ++m)
#pragma unroll
      for (int n = 0; n < 4; ++n)
        acc[m][n] = __builtin_amdgcn_mfma_f32_16x16x32_bf16(af[m], bfr[n],
                                                            acc[m][n], 0, 0, 0);

    asm volatile("s_waitcnt vmcnt(0)" ::: "memory");  // t+1 landed
    BAR();
  }

  // epilogue
#pragma unroll
  for (int m = 0; m < 4; ++m) {
#pragma unroll
    for (int r = 0; r < 4; ++r) {
      const int row = bm * 256 + wr * 64 + m * 16 + l4 * 4 + r;
#pragma unroll
      for (int n = 0; n < 4; ++n) {
        const int col = bn * 256 + wc * 64 + n * 16 + l15;
        const size_t idx = (size_t)row * N + col;
        const float val = acc[m][n][r];
        if constexpr (EPI == 0) {
          ((bf16_t*)C)[idx] = (bf16_t)val;
        } else if constexpr (EPI == 1) {
          ((float*)C)[idx] = ldS(aux, idx, isbf) + val;
        } else if constexpr (EPI == 2) {
          float g = (float)((const bf16_t*)aux)[idx];
          float sg = g / (1.f + __expf(-g));
          ((bf16_t*)C)[idx] = (bf16_t)(sg * val);
        } else {
          float v = ((const float*)aux)[idx] + val;
          if (isbf) ((bf16_t*)C)[idx] = (bf16_t)v;
          else      ((float*)C)[idx] = v;
        }
      }
    }
  }
}

// ---------------------------------------------------------------- attention
__global__ __launch_bounds__(512)
void attn_k(const bf16_t* __restrict__ QKV, const void* __restrict__ sink,
            bf16_t* __restrict__ O, const uint32_t* __restrict__ det) {
  __shared__ __align__(16) bf16_t Ks[64][128];
  __shared__ __align__(16) bf16_t Vt[128][64];
  __shared__ __align__(16) bf16_t Ps[8][32][64];

  const bool isbf = det_bf16(det);
  const int bx = blockIdx.x;
  const int n = bx & (NB_ - 1);
  const int h = (bx >> 4) & (H_ - 1);
  const int b = bx >> 8;
  const int tid = threadIdx.x;
  const int wv = tid >> 6, lane = tid & 63;
  const int l15 = lane & 15, l4 = lane >> 4;
  const size_t qkvbase = (size_t)b * S_ * QS_ + h * HD_;
  const size_t obase = ((size_t)b * S_ * H_ + h) * HD_;
  const int q0 = n * W_;
  const int wq = wv * 32;

  bf16x8 qf[2][4];
#pragma unroll
  for (int mi = 0; mi < 2; ++mi)
#pragma unroll
    for (int kb = 0; kb < 4; ++kb) {
      int s = q0 + wq + mi * 16 + l15;
      qf[mi][kb] = *(const bf16x8*)&QKV[qkvbase + (size_t)s * QS_ + kb * 32 + l4 * 8];
    }

  const float sinkl = ldS(sink, h, isbf);
  float m_run[2][4], l_run[2][4];
#pragma unroll
  for (int mi = 0; mi < 2; ++mi)
#pragma unroll
    for (int r = 0; r < 4; ++r) { m_run[mi][r] = sinkl; l_run[mi][r] = 1.0f; }
  f32x4 oacc[2][8] = {};

  const int kvbase = q0 - W_;
  const float scale = 0.088388347648318447f;  // 1/sqrt(128)

  for (int c = 0; c < 8; ++c) {
    __syncthreads();
#pragma unroll
    for (int rnd = 0; rnd < 2; ++rnd) {
      int chunk = tid + rnd * 512;
      int r = chunk >> 4;
      int c8 = (chunk & 15) << 3;
      int sk = kvbase + c * 64 + r;
      int4 kv = {0, 0, 0, 0}, vvv = {0, 0, 0, 0};
      if (sk >= 0) {
        const bf16_t* src = &QKV[qkvbase + (size_t)sk * QS_ + c8];
        kv = *(const int4*)(src + 2048);
        vvv = *(const int4*)(src + 4096);
      }
      *(int4*)&Ks[r][c8] = kv;
      const bf16_t* pv = (const bf16_t*)&vvv;
#pragma unroll
      for (int j = 0; j < 8; ++j) Vt[c8 + j][r] = pv[j];
    }
    __syncthreads();

    bool any = (c * 64 + 63 >= wq + 1) && (c * 64 <= wq + 31 + W_);
    if (n == 0 && c < 4) any = false;
    if (!any) continue;

    f32x4 sacc[2][4] = {};
#pragma unroll
    for (int kb = 0; kb < 4; ++kb) {
      bf16x8 kf[4];
#pragma unroll
      for (int ni = 0; ni < 4; ++ni)
        kf[ni] = *(const bf16x8*)&Ks[ni * 16 + l15][kb * 32 + l4 * 8];
#pragma unroll
      for (int mi = 0; mi < 2; ++mi)
#pragma unroll
        for (int ni = 0; ni < 4; ++ni)
          sacc[mi][ni] = __builtin_amdgcn_mfma_f32_16x16x32_bf16(
              qf[mi][kb], kf[ni], sacc[mi][ni], 0, 0, 0);
    }

#pragma unroll
    for (int mi = 0; mi < 2; ++mi) {
#pragma unroll
      for (int r = 0; r < 4; ++r) {
        const int qi = wq + mi * 16 + l4 * 4 + r;
        float mx = -3.0e38f;
#pragma unroll
        for (int ni = 0; ni < 4; ++ni) {
          int kj = c * 64 + ni * 16 + l15;
          bool ok = (kj > qi) && (kj <= qi + W_) && (n > 0 || kj >= W_);
          float sv = ok ? sacc[mi][ni][r] * scale : -1.0e30f;
          sacc[mi][ni][r] = sv;
          mx = fmaxf(mx, sv);
        }
#pragma unroll
        for (int off = 1; off < 16; off <<= 1)
          mx = fmaxf(mx, __shfl_xor(mx, off, 64));
        float mo = m_run[mi][r];
        float mn = fmaxf(mo, mx);
        float alpha = __expf(mo - mn);
        m_run[mi][r] = mn;
        float rs = 0.f;
#pragma unroll
        for (int ni = 0; ni < 4; ++ni) {
          float p = __expf(sacc[mi][ni][r] - mn);
          sacc[mi][ni][r] = p;
          rs += p;
        }
#pragma unroll
        for (int off = 1; off < 16; off <<= 1) rs += __shfl_xor(rs, off, 64);
        l_run[mi][r] = l_run[mi][r] * alpha + rs;
#pragma unroll
        for (int ni = 0; ni < 8; ++ni) oacc[mi][ni][r] *= alpha;
      }
    }

#pragma unroll
    for (int mi = 0; mi < 2; ++mi)
#pragma unroll
      for (int ni = 0; ni < 4; ++ni)
#pragma unroll
        for (int r = 0; r < 4; ++r)
          Ps[wv][mi * 16 + l4 * 4 + r][ni * 16 + l15] = (bf16_t)sacc[mi][ni][r];

#pragma unroll
    for (int kb2 = 0; kb2 < 2; ++kb2) {
      bf16x8 pf[2];
#pragma unroll
      for (int mi = 0; mi < 2; ++mi)
        pf[mi] = *(const bf16x8*)&Ps[wv][mi * 16 + l15][kb2 * 32 + l4 * 8];
#pragma unroll
      for (int ni = 0; ni < 8; ++ni) {
        bf16x8 vf = *(const bf16x8*)&Vt[ni * 16 + l15][kb2 * 32 + l4 * 8];
#pragma unroll
        for (int mi = 0; mi < 2; ++mi)
          oacc[mi][ni] = __builtin_amdgcn_mfma_f32_16x16x32_bf16(
              pf[mi], vf, oacc[mi][ni], 0, 0, 0);
      }
    }
  }

#pragma unroll
  for (int mi = 0; mi < 2; ++mi)
#pragma unroll
    for (int r = 0; r < 4; ++r) {
      float inv = 1.0f / l_run[mi][r];
      int s = q0 + wq + mi * 16 + l4 * 4 + r;
#pragma unroll
      for (int ni = 0; ni < 8; ++ni)
        O[obase + (size_t)s * (H_ * HD_) + ni * 16 + l15] =
            (bf16_t)(oacc[mi][ni][r] * inv);
    }
}

// ---------------------------------------------------------------- launcher
extern "C" void kernel_launch(void* const* d_in, const int* in_sizes, int n_in,
                              void* d_out, int out_size, void* d_ws,
                              size_t ws_size, hipStream_t stream) {
  const void* x   = d_in[0];
  const void* Wq  = d_in[1];
  const void* Wk  = d_in[2];
  const void* Wv  = d_in[3];
  const void* Wo  = d_in[4];
  const void* qnw = d_in[5];
  const void* knw = d_in[6];
  const void* snk = d_in[7];
  const void* anw = d_in[8];
  const void* fnw = d_in[9];
  const void* Wg  = d_in[10];
  const void* Wu  = d_in[11];
  const void* Wd  = d_in[12];
  const uint32_t* det = (const uint32_t*)anw;

  char* ws = (char*)d_ws;
  const size_t MB = 1024ull * 1024ull;
  bf16_t* WT  = (bf16_t*)(ws + 0 * MB);    // 32 MB: transposed weight(s)
  bf16_t* hb  = (bf16_t*)(ws + 32 * MB);   // 32 MB: rmsnorm output
  bf16_t* qkv = (bf16_t*)(ws + 64 * MB);   // 96 MB: fused q|k|v [8192][6144]
  bf16_t* ao  = (bf16_t*)(ws + 160 * MB);  // 32 MB: attn out
  float* xm   = (float*)(ws + 192 * MB);   // 64 MB: fp32 residual stream
  bf16_t* gb  = (bf16_t*)(ws + 64 * MB);   // 128 MB, overlays dead qkv/ao

  const int LDSZ = 65536;
  hipFuncSetAttribute((const void*)gemm256_k<0>,
                      hipFuncAttributeMaxDynamicSharedMemorySize, LDSZ);
  hipFuncSetAttribute((const void*)gemm256_k<1>,
                      hipFuncAttributeMaxDynamicSharedMemorySize, LDSZ);
  hipFuncSetAttribute((const void*)gemm256_k<2>,
                      hipFuncAttributeMaxDynamicSharedMemorySize, LDSZ);
  hipFuncSetAttribute((const void*)gemm256_k<3>,
                      hipFuncAttributeMaxDynamicSharedMemorySize, LDSZ);

  // ---- attention sublayer ----
  rmsnorm_in_k<<<ROWS_, 256, 0, stream>>>(x, anw, hb, det);

  // fused QKV: Bt = [Wq^T ; Wk^T ; Wv^T]  (6144 x 2048)
  transpose_k<<<32 * 32, 256, 0, stream>>>(Wq, WT, 2048, 2048, det);
  transpose_k<<<32 * 32, 256, 0, stream>>>(Wk, WT + 2048 * 2048, 2048, 2048, det);
  transpose_k<<<32 * 32, 256, 0, stream>>>(Wv, WT + 2 * 2048 * 2048, 2048, 2048, det);
  gemm256_k<0><<<32 * 24, 1024, LDSZ, stream>>>(hb, WT, qkv, nullptr, det,
                                                8192, 6144, 2048);

  qknorm_rope_k<<<B_ * S_ * H_ / 4, 256, 0, stream>>>(qkv, qnw, knw, det);

  attn_k<<<B_ * H_ * NB_, 512, 0, stream>>>(qkv, snk, ao, det);

  transpose_k<<<32 * 32, 256, 0, stream>>>(Wo, WT, 2048, 2048, det);
  gemm256_k<1><<<32 * 8, 1024, LDSZ, stream>>>(ao, WT, xm, x, det, 8192, 2048, 2048);

  // ---- SwiGLU FFN sublayer ----
  rmsnorm_f32_k<<<ROWS_, 256, 0, stream>>>(xm, fnw, hb, det);

  transpose_k<<<32 * 128, 256, 0, stream>>>(Wg, WT, 2048, 8192, det);
  gemm256_k<0><<<32 * 32, 1024, LDSZ, stream>>>(hb, WT, gb, nullptr, det, 8192, 8192, 2048);
  transpose_k<<<32 * 128, 256, 0, stream>>>(Wu, WT, 2048, 8192, det);
  gemm256_k<2><<<32 * 32, 1024, LDSZ, stream>>>(hb, WT, gb, gb, det, 8192, 8192, 2048);
  transpose_k<<<128 * 32, 256, 0, stream>>>(Wd, WT, 8192, 2048, det);
  gemm256_k<3><<<32 * 8, 1024, LDSZ, stream>>>(gb, WT, d_out, xm, det, 8192, 2048, 8192);

  (void)in_sizes; (void)n_in; (void)out_size; (void)ws_size;
}

// Round 14
// 1189.536 us; speedup vs baseline: 1.1080x; 1.1080x over previous
//
#include <hip/hip_runtime.h>
#include <hip/hip_bf16.h>
#include <stdint.h>

typedef __bf16 bf16_t;
typedef __bf16 bf16x8 __attribute__((ext_vector_type(8)));
typedef float f32x4 __attribute__((ext_vector_type(4)));

#define B_ 2
#define S_ 4096
#define D_ 2048
#define H_ 16
#define HD_ 128
#define FF_ 8192
#define W_ 256
#define NB_ 16            // S_/W_
#define ROWS_ 8192        // B_*S_
#define QS_ 6144          // fused qkv row stride

#define BAR() asm volatile("s_barrier" ::: "memory")

// ------------------------------------------------- dtype-flex input helpers
__device__ __forceinline__ bool det_bf16(const uint32_t* det) {
  return (det[0] & 0xFFFFu) == 0x3F80u;
}
__device__ __forceinline__ float ldS(const void* p, size_t i, bool isbf) {
  return isbf ? (float)((const bf16_t*)p)[i] : ((const float*)p)[i];
}
__device__ __forceinline__ void ld8(const void* p, size_t i, bool isbf,
                                    float* f) {
  if (isbf) {
    bf16x8 v = *(const bf16x8*)((const bf16_t*)p + i);
#pragma unroll
    for (int j = 0; j < 8; ++j) f[j] = (float)v[j];
  } else {
    const float* s = (const float*)p + i;
    float4 a = *(const float4*)s;
    float4 b = *(const float4*)(s + 4);
    f[0] = a.x; f[1] = a.y; f[2] = a.z; f[3] = a.w;
    f[4] = b.x; f[5] = b.y; f[6] = b.z; f[7] = b.w;
  }
}

__device__ __forceinline__ void gld_lds16(const bf16_t* g, bf16_t* l) {
  __builtin_amdgcn_global_load_lds(
      (const __attribute__((address_space(1))) uint32_t*)g,
      (__attribute__((address_space(3))) uint32_t*)l, 16, 0, 0);
}

// ---------------------------------------------------------------- transpose
__global__ __launch_bounds__(256)
void transpose_k(const void* __restrict__ src, bf16_t* __restrict__ dst,
                 int R, int C, const uint32_t* __restrict__ det) {
  __shared__ __align__(16) bf16_t tile[64][72];
  const bool isbf = det_bf16(det);
  const int nbc = C >> 6;
  const int br = blockIdx.x / nbc, bc = blockIdx.x % nbc;
  const int t = threadIdx.x;
#pragma unroll
  for (int rnd = 0; rnd < 2; ++rnd) {
    int chunk = t + rnd * 256;
    int r = chunk >> 3;
    int c8 = (chunk & 7) << 3;
    float f[8];
    ld8(src, (size_t)(br * 64 + r) * C + bc * 64 + c8, isbf, f);
    union { bf16_t e[8]; int4 v; } u;
#pragma unroll
    for (int j = 0; j < 8; ++j) u.e[j] = (bf16_t)f[j];
    *(int4*)&tile[r][c8] = u.v;
  }
  __syncthreads();
#pragma unroll
  for (int rnd = 0; rnd < 2; ++rnd) {
    int chunk = t + rnd * 256;
    int cc = chunk >> 3;
    int r8 = (chunk & 7) << 3;
    union { bf16_t e[8]; int4 v; } u;
#pragma unroll
    for (int j = 0; j < 8; ++j) u.e[j] = tile[r8 + j][cc];
    *(int4*)&dst[(size_t)(bc * 64 + cc) * R + br * 64 + r8] = u.v;
  }
}

// ---------------------------------------------------------------- rmsnorm
__global__ __launch_bounds__(256)
void rmsnorm_in_k(const void* __restrict__ x, const void* __restrict__ w,
                  bf16_t* __restrict__ out, const uint32_t* __restrict__ det) {
  __shared__ float sm[4];
  const bool isbf = det_bf16(det);
  const size_t row = blockIdx.x;
  const int i0 = threadIdx.x << 3;
  float f[8], ss = 0.f;
  ld8(x, row * D_ + i0, isbf, f);
#pragma unroll
  for (int j = 0; j < 8; ++j) ss += f[j] * f[j];
#pragma unroll
  for (int off = 1; off < 64; off <<= 1) ss += __shfl_xor(ss, off, 64);
  if ((threadIdx.x & 63) == 0) sm[threadIdx.x >> 6] = ss;
  __syncthreads();
  float tot = sm[0] + sm[1] + sm[2] + sm[3];
  float rs = rsqrtf(tot * (1.0f / D_) + 1e-6f);
  float wf[8];
  ld8(w, i0, isbf, wf);
  bf16x8 res;
#pragma unroll
  for (int j = 0; j < 8; ++j) res[j] = (bf16_t)(f[j] * rs * wf[j]);
  *(bf16x8*)&out[row * D_ + i0] = res;
}

__global__ __launch_bounds__(256)
void rmsnorm_f32_k(const float* __restrict__ x, const void* __restrict__ w,
                   bf16_t* __restrict__ out, const uint32_t* __restrict__ det) {
  __shared__ float sm[4];
  const bool isbf = det_bf16(det);
  const size_t row = blockIdx.x;
  const int i0 = threadIdx.x << 3;
  float4 a = *(const float4*)&x[row * D_ + i0];
  float4 b = *(const float4*)&x[row * D_ + i0 + 4];
  float f[8] = {a.x, a.y, a.z, a.w, b.x, b.y, b.z, b.w};
  float ss = 0.f;
#pragma unroll
  for (int j = 0; j < 8; ++j) ss += f[j] * f[j];
#pragma unroll
  for (int off = 1; off < 64; off <<= 1) ss += __shfl_xor(ss, off, 64);
  if ((threadIdx.x & 63) == 0) sm[threadIdx.x >> 6] = ss;
  __syncthreads();
  float tot = sm[0] + sm[1] + sm[2] + sm[3];
  float rs = rsqrtf(tot * (1.0f / D_) + 1e-6f);
  float wf[8];
  ld8(w, i0, isbf, wf);
  bf16x8 res;
#pragma unroll
  for (int j = 0; j < 8; ++j) res[j] = (bf16_t)(f[j] * rs * wf[j]);
  *(bf16x8*)&out[row * D_ + i0] = res;
}

// ---------------------------------------------------------------- qk-norm + rope
__global__ __launch_bounds__(256)
void qknorm_rope_k(bf16_t* __restrict__ qkv, const void* __restrict__ qw,
                   const void* __restrict__ kw,
                   const uint32_t* __restrict__ det) {
  const bool isbf = det_bf16(det);
  const int wv = threadIdx.x >> 6;
  const int i = threadIdx.x & 63;
  const int idx = blockIdx.x * 4 + wv;   // (b*S + s)*H + h
  const int row = idx >> 4;              // b*S + s
  const int s = row & (S_ - 1);
  const int h = idx & 15;
  bf16_t* qp = qkv + (size_t)row * QS_ + h * HD_;
  bf16_t* kp = qp + 2048;

  float inv = exp2f((float)i * -0.20762050593046014f);  // 10000^(-i/64)
  float ang = (float)s * inv;
  float sn, cs;
  sincosf(ang, &sn, &cs);

#pragma unroll
  for (int t = 0; t < 2; ++t) {
    bf16_t* p = (t == 0) ? qp : kp;
    const void* w = (t == 0) ? qw : kw;
    float x1 = (float)p[i], x2 = (float)p[i + 64];
    float ss = x1 * x1 + x2 * x2;
#pragma unroll
    for (int off = 1; off < 64; off <<= 1) ss += __shfl_xor(ss, off, 64);
    float rs = rsqrtf(ss * (1.0f / HD_) + 1e-6f);
    float n1 = x1 * rs * ldS(w, i, isbf);
    float n2 = x2 * rs * ldS(w, i + 64, isbf);
    p[i] = (bf16_t)(n1 * cs - n2 * sn);
    p[i + 64] = (bf16_t)(n1 * sn + n2 * cs);
  }
}

// ---------------------------------------------------------------- GEMM 256x256
// 16-wave (1024 thr) 4x4 wave grid, 64x64/wave, BK=64 double-buffer
// (128 KiB LDS). Halves barrier/vmcnt events per unit K vs r13's BK=32
// while keeping 4 waves/SIMD. Sync semantics = validated dbuf:
// stage(t+1)->buf^1, vmcnt(0)+barrier per K-tile. Staging 2 units/thread/
// operand; 16B-unit XOR swizzle (u ^ (r&7), r9-validated); 2D-group map.
#define TQ 16384   // 256*64 elems per operand tile

template <int EPI>
__global__ __launch_bounds__(1024)
void gemm256_k(const bf16_t* __restrict__ A, const bf16_t* __restrict__ Bt,
               void* __restrict__ C, const void* __restrict__ aux,
               const uint32_t* __restrict__ det, int M, int N, int K) {
  extern __shared__ __align__(16) bf16_t lds[];
  bf16_t* Ab = lds;             // [2][256][64]
  bf16_t* Bb = lds + 2 * TQ;    // [2][256][64]

  bool isbf = false;
  if constexpr (EPI == 1 || EPI == 3) isbf = det_bf16(det);

  const int tid = threadIdx.x;
  const int lane = tid & 63, wid = tid >> 6;   // 16 waves
  const int l15 = lane & 15, l4 = lane >> 4;
  const int wr = wid >> 2, wc = wid & 3;       // 4x4 wave grid, 64x64 each

  // T1: bijective XCD swizzle (m204), then 2D group (GM=4)
  const int nwg = gridDim.x;
  const int nbn = N >> 8;
  const int orig = blockIdx.x;
  const int q8 = nwg >> 3, r8 = nwg & 7, xcd = orig & 7;
  const int swz = (xcd < r8 ? xcd * (q8 + 1) : r8 * (q8 + 1) + (xcd - r8) * q8)
                + (orig >> 3);
  const int grp = swz / (4 * nbn);
  const int rem = swz % (4 * nbn);
  const int bm = grp * 4 + (rem & 3);
  const int bn = rem >> 2;

  const bf16_t* Ag = A + (size_t)(bm * 256) * K;
  const bf16_t* Bg = Bt + (size_t)(bn * 256) * K;

  // staging: 2048 16B units per operand tile; 2 per thread
  size_t goff[2];
  int loff[2];
#pragma unroll
  for (int j = 0; j < 2; ++j) {
    int c = tid + j * 1024;
    int r = c >> 3, u = c & 7;
    goff[j] = (size_t)r * K + ((u ^ (r & 7)) << 3);
    loff[j] = c * 8;
  }

  auto stage = [&](int tt) {
    bf16_t* la = Ab + (tt & 1) * TQ;
    bf16_t* lb = Bb + (tt & 1) * TQ;
    const size_t k0 = (size_t)tt << 6;
#pragma unroll
    for (int j = 0; j < 2; ++j) gld_lds16(Ag + k0 + goff[j], la + loff[j]);
#pragma unroll
    for (int j = 0; j < 2; ++j) gld_lds16(Bg + k0 + goff[j], lb + loff[j]);
  };

  // read offsets (elems), thread-constant
  int aoff[4][2], boff[4][2];
#pragma unroll
  for (int m = 0; m < 4; ++m) {
    int R = wr * 64 + m * 16 + l15;
#pragma unroll
    for (int ks = 0; ks < 2; ++ks)
      aoff[m][ks] = R * 64 + ((((ks << 2) | l4) ^ (R & 7)) << 3);
  }
#pragma unroll
  for (int n = 0; n < 4; ++n) {
    int R = wc * 64 + n * 16 + l15;
#pragma unroll
    for (int ks = 0; ks < 2; ++ks)
      boff[n][ks] = R * 64 + ((((ks << 2) | l4) ^ (R & 7)) << 3);
  }

  f32x4 acc[4][4] = {};
  const int nt = K >> 6;

  // prologue: stage tile 0
  stage(0);
  asm volatile("s_waitcnt vmcnt(0)" ::: "memory");
  BAR();

  for (int t = 0; t < nt; ++t) {
    const bf16_t* a = Ab + (t & 1) * TQ;
    const bf16_t* b = Bb + (t & 1) * TQ;

    if (t + 1 < nt) stage(t + 1);   // into the other buffer

#pragma unroll
    for (int ks = 0; ks < 2; ++ks) {
      bf16x8 af[4], bfr[4];
#pragma unroll
      for (int n = 0; n < 4; ++n) bfr[n] = *(const bf16x8*)&b[boff[n][ks]];
#pragma unroll
      for (int m = 0; m < 4; ++m) af[m] = *(const bf16x8*)&a[aoff[m][ks]];
#pragma unroll
      for (int m = 0; m < 4; ++m)
#pragma unroll
        for (int n = 0; n < 4; ++n)
          acc[m][n] = __builtin_amdgcn_mfma_f32_16x16x32_bf16(af[m], bfr[n],
                                                              acc[m][n], 0, 0, 0);
    }

    asm volatile("s_waitcnt vmcnt(0)" ::: "memory");  // t+1 landed
    BAR();
  }

  // epilogue
#pragma unroll
  for (int m = 0; m < 4; ++m) {
#pragma unroll
    for (int r = 0; r < 4; ++r) {
      const int row = bm * 256 + wr * 64 + m * 16 + l4 * 4 + r;
#pragma unroll
      for (int n = 0; n < 4; ++n) {
        const int col = bn * 256 + wc * 64 + n * 16 + l15;
        const size_t idx = (size_t)row * N + col;
        const float val = acc[m][n][r];
        if constexpr (EPI == 0) {
          ((bf16_t*)C)[idx] = (bf16_t)val;
        } else if constexpr (EPI == 1) {
          ((float*)C)[idx] = ldS(aux, idx, isbf) + val;
        } else if constexpr (EPI == 2) {
          float g = (float)((const bf16_t*)aux)[idx];
          float sg = g / (1.f + __expf(-g));
          ((bf16_t*)C)[idx] = (bf16_t)(sg * val);
        } else {
          float v = ((const float*)aux)[idx] + val;
          if (isbf) ((bf16_t*)C)[idx] = (bf16_t)v;
          else      ((float*)C)[idx] = v;
        }
      }
    }
  }
}

// ---------------------------------------------------------------- attention
__global__ __launch_bounds__(512)
void attn_k(const bf16_t* __restrict__ QKV, const void* __restrict__ sink,
            bf16_t* __restrict__ O, const uint32_t* __restrict__ det) {
  __shared__ __align__(16) bf16_t Ks[64][128];
  __shared__ __align__(16) bf16_t Vt[128][64];
  __shared__ __align__(16) bf16_t Ps[8][32][64];

  const bool isbf = det_bf16(det);
  const int bx = blockIdx.x;
  const int n = bx & (NB_ - 1);
  const int h = (bx >> 4) & (H_ - 1);
  const int b = bx >> 8;
  const int tid = threadIdx.x;
  const int wv = tid >> 6, lane = tid & 63;
  const int l15 = lane & 15, l4 = lane >> 4;
  const size_t qkvbase = (size_t)b * S_ * QS_ + h * HD_;
  const size_t obase = ((size_t)b * S_ * H_ + h) * HD_;
  const int q0 = n * W_;
  const int wq = wv * 32;

  bf16x8 qf[2][4];
#pragma unroll
  for (int mi = 0; mi < 2; ++mi)
#pragma unroll
    for (int kb = 0; kb < 4; ++kb) {
      int s = q0 + wq + mi * 16 + l15;
      qf[mi][kb] = *(const bf16x8*)&QKV[qkvbase + (size_t)s * QS_ + kb * 32 + l4 * 8];
    }

  const float sinkl = ldS(sink, h, isbf);
  float m_run[2][4], l_run[2][4];
#pragma unroll
  for (int mi = 0; mi < 2; ++mi)
#pragma unroll
    for (int r = 0; r < 4; ++r) { m_run[mi][r] = sinkl; l_run[mi][r] = 1.0f; }
  f32x4 oacc[2][8] = {};

  const int kvbase = q0 - W_;
  const float scale = 0.088388347648318447f;  // 1/sqrt(128)

  for (int c = 0; c < 8; ++c) {
    __syncthreads();
#pragma unroll
    for (int rnd = 0; rnd < 2; ++rnd) {
      int chunk = tid + rnd * 512;
      int r = chunk >> 4;
      int c8 = (chunk & 15) << 3;
      int sk = kvbase + c * 64 + r;
      int4 kv = {0, 0, 0, 0}, vvv = {0, 0, 0, 0};
      if (sk >= 0) {
        const bf16_t* src = &QKV[qkvbase + (size_t)sk * QS_ + c8];
        kv = *(const int4*)(src + 2048);
        vvv = *(const int4*)(src + 4096);
      }
      *(int4*)&Ks[r][c8] = kv;
      const bf16_t* pv = (const bf16_t*)&vvv;
#pragma unroll
      for (int j = 0; j < 8; ++j) Vt[c8 + j][r] = pv[j];
    }
    __syncthreads();

    bool any = (c * 64 + 63 >= wq + 1) && (c * 64 <= wq + 31 + W_);
    if (n == 0 && c < 4) any = false;
    if (!any) continue;

    f32x4 sacc[2][4] = {};
#pragma unroll
    for (int kb = 0; kb < 4; ++kb) {
      bf16x8 kf[4];
#pragma unroll
      for (int ni = 0; ni < 4; ++ni)
        kf[ni] = *(const bf16x8*)&Ks[ni * 16 + l15][kb * 32 + l4 * 8];
#pragma unroll
      for (int mi = 0; mi < 2; ++mi)
#pragma unroll
        for (int ni = 0; ni < 4; ++ni)
          sacc[mi][ni] = __builtin_amdgcn_mfma_f32_16x16x32_bf16(
              qf[mi][kb], kf[ni], sacc[mi][ni], 0, 0, 0);
    }

#pragma unroll
    for (int mi = 0; mi < 2; ++mi) {
#pragma unroll
      for (int r = 0; r < 4; ++r) {
        const int qi = wq + mi * 16 + l4 * 4 + r;
        float mx = -3.0e38f;
#pragma unroll
        for (int ni = 0; ni < 4; ++ni) {
          int kj = c * 64 + ni * 16 + l15;
          bool ok = (kj > qi) && (kj <= qi + W_) && (n > 0 || kj >= W_);
          float sv = ok ? sacc[mi][ni][r] * scale : -1.0e30f;
          sacc[mi][ni][r] = sv;
          mx = fmaxf(mx, sv);
        }
#pragma unroll
        for (int off = 1; off < 16; off <<= 1)
          mx = fmaxf(mx, __shfl_xor(mx, off, 64));
        float mo = m_run[mi][r];
        float mn = fmaxf(mo, mx);
        float alpha = __expf(mo - mn);
        m_run[mi][r] = mn;
        float rs = 0.f;
#pragma unroll
        for (int ni = 0; ni < 4; ++ni) {
          float p = __expf(sacc[mi][ni][r] - mn);
          sacc[mi][ni][r] = p;
          rs += p;
        }
#pragma unroll
        for (int off = 1; off < 16; off <<= 1) rs += __shfl_xor(rs, off, 64);
        l_run[mi][r] = l_run[mi][r] * alpha + rs;
#pragma unroll
        for (int ni = 0; ni < 8; ++ni) oacc[mi][ni][r] *= alpha;
      }
    }

#pragma unroll
    for (int mi = 0; mi < 2; ++mi)
#pragma unroll
      for (int ni = 0; ni < 4; ++ni)
#pragma unroll
        for (int r = 0; r < 4; ++r)
          Ps[wv][mi * 16 + l4 * 4 + r][ni * 16 + l15] = (bf16_t)sacc[mi][ni][r];

#pragma unroll
    for (int kb2 = 0; kb2 < 2; ++kb2) {
      bf16x8 pf[2];
#pragma unroll
      for (int mi = 0; mi < 2; ++mi)
        pf[mi] = *(const bf16x8*)&Ps[wv][mi * 16 + l15][kb2 * 32 + l4 * 8];
#pragma unroll
      for (int ni = 0; ni < 8; ++ni) {
        bf16x8 vf = *(const bf16x8*)&Vt[ni * 16 + l15][kb2 * 32 + l4 * 8];
#pragma unroll
        for (int mi = 0; mi < 2; ++mi)
          oacc[mi][ni] = __builtin_amdgcn_mfma_f32_16x16x32_bf16(
              pf[mi], vf, oacc[mi][ni], 0, 0, 0);
      }
    }
  }

#pragma unroll
  for (int mi = 0; mi < 2; ++mi)
#pragma unroll
    for (int r = 0; r < 4; ++r) {
      float inv = 1.0f / l_run[mi][r];
      int s = q0 + wq + mi * 16 + l4 * 4 + r;
#pragma unroll
      for (int ni = 0; ni < 8; ++ni)
        O[obase + (size_t)s * (H_ * HD_) + ni * 16 + l15] =
            (bf16_t)(oacc[mi][ni][r] * inv);
    }
}

// ---------------------------------------------------------------- launcher
extern "C" void kernel_launch(void* const* d_in, const int* in_sizes, int n_in,
                              void* d_out, int out_size, void* d_ws,
                              size_t ws_size, hipStream_t stream) {
  const void* x   = d_in[0];
  const void* Wq  = d_in[1];
  const void* Wk  = d_in[2];
  const void* Wv  = d_in[3];
  const void* Wo  = d_in[4];
  const void* qnw = d_in[5];
  const void* knw = d_in[6];
  const void* snk = d_in[7];
  const void* anw = d_in[8];
  const void* fnw = d_in[9];
  const void* Wg  = d_in[10];
  const void* Wu  = d_in[11];
  const void* Wd  = d_in[12];
  const uint32_t* det = (const uint32_t*)anw;

  char* ws = (char*)d_ws;
  const size_t MB = 1024ull * 1024ull;
  bf16_t* WT  = (bf16_t*)(ws + 0 * MB);    // 32 MB: transposed weight(s)
  bf16_t* hb  = (bf16_t*)(ws + 32 * MB);   // 32 MB: rmsnorm output
  bf16_t* qkv = (bf16_t*)(ws + 64 * MB);   // 96 MB: fused q|k|v [8192][6144]
  bf16_t* ao  = (bf16_t*)(ws + 160 * MB);  // 32 MB: attn out
  float* xm   = (float*)(ws + 192 * MB);   // 64 MB: fp32 residual stream
  bf16_t* gb  = (bf16_t*)(ws + 64 * MB);   // 128 MB, overlays dead qkv/ao

  const int LDSZ = 131072;
  hipFuncSetAttribute((const void*)gemm256_k<0>,
                      hipFuncAttributeMaxDynamicSharedMemorySize, LDSZ);
  hipFuncSetAttribute((const void*)gemm256_k<1>,
                      hipFuncAttributeMaxDynamicSharedMemorySize, LDSZ);
  hipFuncSetAttribute((const void*)gemm256_k<2>,
                      hipFuncAttributeMaxDynamicSharedMemorySize, LDSZ);
  hipFuncSetAttribute((const void*)gemm256_k<3>,
                      hipFuncAttributeMaxDynamicSharedMemorySize, LDSZ);

  // ---- attention sublayer ----
  rmsnorm_in_k<<<ROWS_, 256, 0, stream>>>(x, anw, hb, det);

  // fused QKV: Bt = [Wq^T ; Wk^T ; Wv^T]  (6144 x 2048)
  transpose_k<<<32 * 32, 256, 0, stream>>>(Wq, WT, 2048, 2048, det);
  transpose_k<<<32 * 32, 256, 0, stream>>>(Wk, WT + 2048 * 2048, 2048, 2048, det);
  transpose_k<<<32 * 32, 256, 0, stream>>>(Wv, WT + 2 * 2048 * 2048, 2048, 2048, det);
  gemm256_k<0><<<32 * 24, 1024, LDSZ, stream>>>(hb, WT, qkv, nullptr, det,
                                                8192, 6144, 2048);

  qknorm_rope_k<<<B_ * S_ * H_ / 4, 256, 0, stream>>>(qkv, qnw, knw, det);

  attn_k<<<B_ * H_ * NB_, 512, 0, stream>>>(qkv, snk, ao, det);

  transpose_k<<<32 * 32, 256, 0, stream>>>(Wo, WT, 2048, 2048, det);
  gemm256_k<1><<<32 * 8, 1024, LDSZ, stream>>>(ao, WT, xm, x, det, 8192, 2048, 2048);

  // ---- SwiGLU FFN sublayer ----
  rmsnorm_f32_k<<<ROWS_, 256, 0, stream>>>(xm, fnw, hb, det);

  transpose_k<<<32 * 128, 256, 0, stream>>>(Wg, WT, 2048, 8192, det);
  gemm256_k<0><<<32 * 32, 1024, LDSZ, stream>>>(hb, WT, gb, nullptr, det, 8192, 8192, 2048);
  transpose_k<<<32 * 128, 256, 0, stream>>>(Wu, WT, 2048, 8192, det);
  gemm256_k<2><<<32 * 32, 1024, LDSZ, stream>>>(hb, WT, gb, gb, det, 8192, 8192, 2048);
  transpose_k<<<128 * 32, 256, 0, stream>>>(Wd, WT, 8192, 2048, det);
  gemm256_k<3><<<32 * 8, 1024, LDSZ, stream>>>(gb, WT, d_out, xm, det, 8192, 2048, 8192);

  (void)in_sizes; (void)n_in; (void)out_size; (void)ws_size;
}